// Round 1
// baseline (295.998 us; speedup 1.0000x reference)
//
#include <hip/hip_runtime.h>

// Problem constants: B=8, H=8, L=2048, D=64, num_delays=16
static constexpr int LSEQ = 2048;
static constexpr int NB   = 8;
static constexpr int NH   = 8;
static constexpr int ND   = 64;
static constexpr int NDEL = 16;

// ws layout:
//   S     : float2[8][1025]  at byte 0        (65600 B)  -- freq-domain accumulator
//   w     : float [8][16]    at byte 65600    (512 B)
//   delay : int   [8][16]    at byte 66112    (512 B)
static constexpr size_t WS_S_OFF     = 0;
static constexpr size_t WS_W_OFF     = 65600;
static constexpr size_t WS_DELAY_OFF = 66112;

// ---------------------------------------------------------------------------
// Kernel A: per (b, h, d-pair) block. z = q + i*k, 2048-pt radix-2 DIF FFT in
// LDS (natural input -> bit-reversed output). Extract Qf, Kf via the
// two-for-one trick reading positions rev(f), rev(L-f), accumulate
// S[b][f] += Qf * conj(Kf) over channels with fp32 atomics.
// ---------------------------------------------------------------------------
__global__ __launch_bounds__(256) void fft_corr(const float* __restrict__ q,
                                                const float* __restrict__ k,
                                                float2* __restrict__ S) {
    const int tid    = threadIdx.x;
    const int blk    = blockIdx.x;       // 2048 blocks = 8 b * 8 h * 32 dchunks
    const int dchunk = blk & 31;
    const int h      = (blk >> 5) & 7;
    const int b      = blk >> 8;
    const size_t base = ((size_t)(b * NH + h)) * LSEQ * ND + (size_t)(dchunk * 2);

    __shared__ float2 z[2][LSEQ];        // 32 KiB: [channel][t]

    // Load: z[ch][t] = q[t, d0+ch] + i * k[t, d0+ch]
    for (int t = tid; t < LSEQ; t += 256) {
        const float2 qv = *(const float2*)(q + base + (size_t)t * ND);
        const float2 kv = *(const float2*)(k + base + (size_t)t * ND);
        z[0][t] = make_float2(qv.x, kv.x);
        z[1][t] = make_float2(qv.y, kv.y);
    }
    __syncthreads();

    // DIF FFT: 11 stages, 2 ch * 1024 butterflies = 2048 per stage, 8/thread.
    for (int M = LSEQ; M >= 2; M >>= 1) {
        const int   half = M >> 1;
        const float w0   = -6.28318530717958647692f / (float)M;
        #pragma unroll
        for (int u = 0; u < 8; ++u) {
            const int g  = u * 256 + tid;
            const int ch = g >> 10;
            const int j  = g & 1023;
            const int kk = j & (half - 1);
            const int i0 = 2 * j - kk;    // (j/half)*M + (j%half)
            const int i1 = i0 + half;
            const float2 a = z[ch][i0];
            const float2 c = z[ch][i1];
            float sn, cs;
            __sincosf(w0 * (float)kk, &sn, &cs);
            const float dx = a.x - c.x, dy = a.y - c.y;
            z[ch][i0] = make_float2(a.x + c.x, a.y + c.y);
            z[ch][i1] = make_float2(dx * cs - dy * sn, dx * sn + dy * cs);
        }
        __syncthreads();
    }

    // Product phase: S[f] += sum_ch Qf * conj(Kf), f = 0..1024.
    for (int f = tid; f <= LSEQ / 2; f += 256) {
        const int rf = (int)(__brev((unsigned)f) >> 21);
        const int rm = (int)(__brev((unsigned)((LSEQ - f) & (LSEQ - 1))) >> 21);
        float sr = 0.f, si = 0.f;
        #pragma unroll
        for (int ch = 0; ch < 2; ++ch) {
            const float2 Zf = z[ch][rf];
            const float2 Zm = z[ch][rm];
            const float qr = 0.5f * (Zf.x + Zm.x);
            const float qi = 0.5f * (Zf.y - Zm.y);
            const float kr = 0.5f * (Zf.y + Zm.y);
            const float ki = 0.5f * (Zm.x - Zf.x);
            sr += qr * kr + qi * ki;
            si += qi * kr - qr * ki;
        }
        atomicAdd(&S[b * 1025 + f].x, sr);
        atomicAdd(&S[b * 1025 + f].y, si);
    }
}

// ---------------------------------------------------------------------------
// Kernel B: one block per batch. Hermitian-extend S into bit-reversed order,
// inverse DIT FFT (bit-reversed input -> natural output), scale, then
// iterative top-16 (ties -> smaller index, matching lax.top_k) + softmax.
// ---------------------------------------------------------------------------
__global__ __launch_bounds__(256) void ifft_topk(const float2* __restrict__ S,
                                                 float* __restrict__ wout,
                                                 int* __restrict__ dout) {
    const int b   = blockIdx.x;
    const int tid = threadIdx.x;

    __shared__ float2 y[LSEQ];           // 16 KiB
    __shared__ float  mc[LSEQ];          // 8 KiB
    __shared__ float  rv[256];
    __shared__ int    ri[256];
    __shared__ float  topv[NDEL];
    __shared__ int    topi[NDEL];

    // Fill y at bit-reversed positions with Hermitian completion.
    for (int f = tid; f <= LSEQ / 2; f += 256) {
        const float2 s = S[b * 1025 + f];
        y[__brev((unsigned)f) >> 21] = s;
        if (f >= 1 && f <= LSEQ / 2 - 1)
            y[__brev((unsigned)(LSEQ - f)) >> 21] = make_float2(s.x, -s.y);
    }
    __syncthreads();

    // Inverse DIT FFT: 1024 butterflies / stage, 4 per thread.
    for (int M = 2; M <= LSEQ; M <<= 1) {
        const int   half = M >> 1;
        const float w0   = 6.28318530717958647692f / (float)M;
        #pragma unroll
        for (int u = 0; u < 4; ++u) {
            const int j  = u * 256 + tid;
            const int kk = j & (half - 1);
            const int i0 = 2 * j - kk;
            const int i1 = i0 + half;
            const float2 a  = y[i0];
            const float2 bb = y[i1];
            float sn, cs;
            __sincosf(w0 * (float)kk, &sn, &cs);
            const float tx = bb.x * cs - bb.y * sn;
            const float ty = bb.x * sn + bb.y * cs;
            y[i0] = make_float2(a.x + tx, a.y + ty);
            y[i1] = make_float2(a.x - tx, a.y - ty);
        }
        __syncthreads();
    }

    // mean_corr[tau] = Re(y[tau]) / (L * H * D)
    const float scale = 1.0f / ((float)LSEQ * (float)(NH * ND));
    for (int t = tid; t < LSEQ; t += 256) mc[t] = y[t].x * scale;
    __syncthreads();

    // Top-16 by iterative argmax (tie -> smaller index).
    for (int it = 0; it < NDEL; ++it) {
        float bv = -1e30f;
        int   bi = 0;
        for (int t = tid; t < LSEQ; t += 256) {
            const float v = mc[t];
            if (v > bv || (v == bv && t < bi)) { bv = v; bi = t; }
        }
        rv[tid] = bv; ri[tid] = bi;
        __syncthreads();
        for (int s = 128; s > 0; s >>= 1) {
            if (tid < s) {
                const float ov = rv[tid + s];
                const int   oi = ri[tid + s];
                if (ov > rv[tid] || (ov == rv[tid] && oi < ri[tid])) {
                    rv[tid] = ov; ri[tid] = oi;
                }
            }
            __syncthreads();
        }
        if (tid == 0) {
            topv[it] = rv[0];
            topi[it] = ri[0];
            mc[ri[0]] = -1e30f;
        }
        __syncthreads();
    }

    // Softmax over the 16 values (descending; topv[0] is the max).
    if (tid == 0) {
        const float m = topv[0];
        float e[NDEL], sum = 0.f;
        for (int i = 0; i < NDEL; ++i) { e[i] = __expf(topv[i] - m); sum += e[i]; }
        const float inv = 1.0f / sum;
        for (int i = 0; i < NDEL; ++i) {
            wout[b * NDEL + i] = e[i] * inv;
            dout[b * NDEL + i] = topi[i];
        }
    }
}

// ---------------------------------------------------------------------------
// Kernel C: out[b,h,t,d] = sum_k w[b,k] * v[b,h,(t+delay[b,k]) & 2047, d]
// One block = one (b,h) slice, 16 t-rows, float4 per thread.
// ---------------------------------------------------------------------------
__global__ __launch_bounds__(256) void gather_out(const float* __restrict__ v,
                                                  const float* __restrict__ w,
                                                  const int* __restrict__ delay,
                                                  float* __restrict__ out) {
    const int blk = blockIdx.x;          // 8192 = 64 (b,h) * 128 t-tiles
    const int bh  = blk >> 7;
    const int bt  = blk & 127;
    const int b   = bh >> 3;
    const int tid = threadIdx.x;

    __shared__ float sw[NDEL];
    __shared__ int   sd[NDEL];
    if (tid < NDEL) {
        sw[tid] = w[b * NDEL + tid];
        sd[tid] = delay[b * NDEL + tid];
    }
    __syncthreads();

    const float* vb = v + (size_t)bh * LSEQ * ND;
    float*       ob = out + (size_t)bh * LSEQ * ND;

    const int row = tid >> 4;            // 0..15
    const int col = (tid & 15) * 4;      // 0..60
    const int t   = bt * 16 + row;

    float4 acc = make_float4(0.f, 0.f, 0.f, 0.f);
    #pragma unroll
    for (int kk = 0; kk < NDEL; ++kk) {
        const int r = (t + sd[kk]) & (LSEQ - 1);
        const float4 vv = *(const float4*)(vb + (size_t)r * ND + col);
        const float wv = sw[kk];
        acc.x += wv * vv.x; acc.y += wv * vv.y;
        acc.z += wv * vv.z; acc.w += wv * vv.w;
    }
    *(float4*)(ob + (size_t)t * ND + col) = acc;
}

// ---------------------------------------------------------------------------
extern "C" void kernel_launch(void* const* d_in, const int* in_sizes, int n_in,
                              void* d_out, int out_size, void* d_ws, size_t ws_size,
                              hipStream_t stream) {
    const float* q = (const float*)d_in[0];
    const float* k = (const float*)d_in[1];
    const float* v = (const float*)d_in[2];
    float* out = (float*)d_out;

    float2* S     = (float2*)((char*)d_ws + WS_S_OFF);
    float*  w     = (float*)((char*)d_ws + WS_W_OFF);
    int*    delay = (int*)((char*)d_ws + WS_DELAY_OFF);

    // Zero the frequency-domain accumulator (ws is poisoned each call).
    hipMemsetAsync(d_ws, 0, (size_t)NB * 1025 * sizeof(float2), stream);

    fft_corr<<<dim3(NB * NH * 32), dim3(256), 0, stream>>>(q, k, S);
    ifft_topk<<<dim3(NB), dim3(256), 0, stream>>>(S, w, delay);
    gather_out<<<dim3(NB * NH * 128), dim3(256), 0, stream>>>(v, w, delay, out);
}

// Round 2
// 221.784 us; speedup vs baseline: 1.3346x; 1.3346x over previous
//
#include <hip/hip_runtime.h>

// B=8, H=8, L=2048, D=64, num_delays=16
static constexpr int LSEQ = 2048;
static constexpr int NB   = 8;
static constexpr int NH   = 8;
static constexpr int ND   = 64;
static constexpr int NDEL = 16;

// ws layout:
//   S     : float2[8][2048] at 0       (131072 B)  full spectrum, bit-reversed order
//   w     : float [8][16]   at 131072  (512 B)
//   delay : int   [8][16]   at 131584  (512 B)
static constexpr size_t WS_S_OFF     = 0;
static constexpr size_t WS_W_OFF     = 131072;
static constexpr size_t WS_DELAY_OFF = 131584;

// Bank swizzle: XOR bits 5,6 -> 3,4 and bits 7,8 -> 1,2. Keeps all FFT stage
// access patterns <=4-way (mostly 2-way = free per m136).
__device__ __forceinline__ int SW(int i) {
    return i ^ ((i >> 2) & 24) ^ ((i >> 6) & 6);
}

// ---------------------------------------------------------------------------
// Kernel A: block = (b,h, d-quad). 4 complex channels z_d = q_d + i*k_d.
// Radix-4 DIF x4 (M=2048,512,128,32) + constant-twiddle radix-8 (M=8,4,2).
// Product phase computes P[f] = Q conj(K) for ALL f in [0,2048), summed over
// the 4 channels, atomically accumulated into S at BIT-REVERSED positions
// (i.e. directly in DIT-input order for kernel B).
// ---------------------------------------------------------------------------
__global__ __launch_bounds__(256) void fft_corr(const float* __restrict__ q,
                                                const float* __restrict__ k,
                                                float2* __restrict__ S) {
    __shared__ float lds[8 * 2048];   // planes: 0..3 = re(ch), 4..7 = im(ch)
    const int tid  = threadIdx.x;
    const int bi   = blockIdx.x;      // 1024 = 64 bh * 16 dquads
    const int xcd  = bi & 7;
    const int slot = bi >> 3;         // 0..127
    const int bh   = xcd * 8 + (slot >> 4);   // same-(b,h) siblings share an XCD
    const int dq   = slot & 15;
    const int b    = bh >> 3;
    const size_t base = (size_t)bh * LSEQ * ND + (size_t)(dq * 4);

    // ---- load 8 rows/thread (all loads in flight before LDS writes) ----
    float4 qv[8], kv[8];
    #pragma unroll
    for (int u = 0; u < 8; ++u) {
        const int t = tid + 256 * u;
        qv[u] = *(const float4*)(q + base + (size_t)t * ND);
        kv[u] = *(const float4*)(k + base + (size_t)t * ND);
    }
    #pragma unroll
    for (int u = 0; u < 8; ++u) {
        const int s1 = SW(tid + 256 * u);
        #pragma unroll
        for (int c = 0; c < 4; ++c) {
            lds[(c << 11)       | (s1 ^ c)]       = (&qv[u].x)[c];  // re plane c
            lds[((c + 4) << 11) | (s1 ^ (c + 4))] = (&kv[u].x)[c];  // im plane c+4
        }
    }
    __syncthreads();

    const int ch   = tid >> 6;        // wave per channel
    const int lane = tid & 63;
    const int reb  = ch << 11;        // plane bases
    const int imb  = (ch + 4) << 11;
    const int rex  = ch;              // per-plane XOR rotate
    const int imx  = ch + 4;

    // ---- 4 radix-4 DIF stages: M = 2048, 512, 128, 32 ----
    #pragma unroll
    for (int s = 0; s < 4; ++s) {
        const int   lq = 9 - 2 * s;           // log2(M/4)
        const int   qq = 1 << lq;
        const float w0 = -6.28318530717958647692f / (float)(qq << 2);
        #pragma unroll
        for (int u = 0; u < 8; ++u) {
            const int j  = lane + 64 * u;     // 512 butterflies/channel
            const int kk = j & (qq - 1);
            const int i0 = ((j >> lq) << (lq + 2)) | kk;
            const int s0 = SW(i0), sA = SW(i0 + qq), sB = SW(i0 + 2 * qq), sC = SW(i0 + 3 * qq);
            const int r0 = reb | (s0 ^ rex), r1 = reb | (sA ^ rex),
                      r2 = reb | (sB ^ rex), r3 = reb | (sC ^ rex);
            const int m0 = imb | (s0 ^ imx), m1 = imb | (sA ^ imx),
                      m2 = imb | (sB ^ imx), m3 = imb | (sC ^ imx);
            const float x0r = lds[r0], x0i = lds[m0], x1r = lds[r1], x1i = lds[m1];
            const float x2r = lds[r2], x2i = lds[m2], x3r = lds[r3], x3i = lds[m3];
            float sn, cs;
            __sincosf(w0 * (float)kk, &sn, &cs);
            const float c2 = cs * cs - sn * sn, s2 = 2.f * cs * sn;   // w2 = w1^2
            const float Ar = x0r + x2r, Ai = x0i + x2i;
            const float B0r = x0r - x2r, B0i = x0i - x2i;
            const float Cr = x1r + x3r, Ci = x1i + x3i;
            const float D0r = x1r - x3r, D0i = x1i - x3i;
            lds[r0] = Ar + Cr; lds[m0] = Ai + Ci;
            const float T1r = Ar - Cr, T1i = Ai - Ci;
            lds[r1] = T1r * c2 - T1i * s2; lds[m1] = T1r * s2 + T1i * c2;
            const float Br = B0r * cs - B0i * sn, Bi = B0r * sn + B0i * cs;  // B0*w1
            const float Dr = D0r * sn + D0i * cs, Di = D0i * sn - D0r * cs;  // D0*w1*(-i)
            lds[r2] = Br + Dr; lds[m2] = Bi + Di;
            const float T3r = Br - Dr, T3i = Bi - Di;
            lds[r3] = T3r * c2 - T3i * s2; lds[m3] = T3r * s2 + T3i * c2;
        }
        __syncthreads();
    }

    // ---- radix-8 tail (stages M=8,4,2), constant twiddles ----
    const float RH = 0.70710678118654752440f;
    #pragma unroll
    for (int u = 0; u < 4; ++u) {          // channel u, group g = tid
        const int pb = tid << 3;
        int rp[8], ip[8];
        #pragma unroll
        for (int c = 0; c < 8; ++c) {
            const int s1 = SW(pb + c);
            rp[c] = (u << 11) | (s1 ^ u);
            ip[c] = ((u + 4) << 11) | (s1 ^ (u + 4));
        }
        float er[8], ei[8];
        #pragma unroll
        for (int c = 0; c < 8; ++c) { er[c] = lds[rp[c]]; ei[c] = lds[ip[c]]; }
        float ur[4], ui[4], vr[4], vi[4];
        ur[0] = er[0] + er[4]; ui[0] = ei[0] + ei[4];
        vr[0] = er[0] - er[4]; vi[0] = ei[0] - ei[4];
        { const float a = er[1] - er[5], bq = ei[1] - ei[5];       // * (r - i r)
          ur[1] = er[1] + er[5]; ui[1] = ei[1] + ei[5];
          vr[1] = RH * (a + bq); vi[1] = RH * (bq - a); }
        { const float a = er[2] - er[6], bq = ei[2] - ei[6];       // * (-i)
          ur[2] = er[2] + er[6]; ui[2] = ei[2] + ei[6];
          vr[2] = bq; vi[2] = -a; }
        { const float a = er[3] - er[7], bq = ei[3] - ei[7];       // * (-r - i r)
          ur[3] = er[3] + er[7]; ui[3] = ei[3] + ei[7];
          vr[3] = RH * (bq - a); vi[3] = -RH * (a + bq); }
        {
            const float a0r = ur[0] + ur[2], a0i = ui[0] + ui[2];
            const float a2r = ur[0] - ur[2], a2i = ui[0] - ui[2];
            const float a1r = ur[1] + ur[3], a1i = ui[1] + ui[3];
            const float a3r = ui[1] - ui[3], a3i = -(ur[1] - ur[3]);  // *( -i )
            lds[rp[0]] = a0r + a1r; lds[ip[0]] = a0i + a1i;
            lds[rp[1]] = a0r - a1r; lds[ip[1]] = a0i - a1i;
            lds[rp[2]] = a2r + a3r; lds[ip[2]] = a2i + a3i;
            lds[rp[3]] = a2r - a3r; lds[ip[3]] = a2i - a3i;
        }
        {
            const float a0r = vr[0] + vr[2], a0i = vi[0] + vi[2];
            const float a2r = vr[0] - vr[2], a2i = vi[0] - vi[2];
            const float a1r = vr[1] + vr[3], a1i = vi[1] + vi[3];
            const float a3r = vi[1] - vi[3], a3i = -(vr[1] - vr[3]);
            lds[rp[4]] = a0r + a1r; lds[ip[4]] = a0i + a1i;
            lds[rp[5]] = a0r - a1r; lds[ip[5]] = a0i - a1i;
            lds[rp[6]] = a2r + a3r; lds[ip[6]] = a2i + a3i;
            lds[rp[7]] = a2r - a3r; lds[ip[7]] = a2i - a3i;
        }
    }
    __syncthreads();

    // ---- product: all 2048 freqs, lane mapping f = fb + 32*lane keeps LDS
    //      reads (rev positions) and atomics conflict-free/coalesced ----
    #pragma unroll
    for (int u = 0; u < 8; ++u) {
        const int fb = (tid >> 6) * 8 + u;           // 0..31
        const int f  = fb + (lane << 5);
        const int m  = (2048 - f) & 2047;
        const int p  = (int)(__brev((unsigned)f) >> 21);   // BR position (also S slot)
        const int pm = (int)(__brev((unsigned)m) >> 21);
        const int sf = SW(p), sm = SW(pm);
        float sr = 0.f, si = 0.f;
        #pragma unroll
        for (int c = 0; c < 4; ++c) {
            const float Zfx = lds[(c << 11) | (sf ^ c)];
            const float Zfy = lds[((c + 4) << 11) | (sf ^ (c + 4))];
            const float Zmx = lds[(c << 11) | (sm ^ c)];
            const float Zmy = lds[((c + 4) << 11) | (sm ^ (c + 4))];
            const float qr = 0.5f * (Zfx + Zmx), qi = 0.5f * (Zfy - Zmy);
            const float kr = 0.5f * (Zfy + Zmy), ki = 0.5f * (Zmx - Zfx);
            sr += qr * kr + qi * ki;
            si += qi * kr - qr * ki;
        }
        atomicAdd(&S[b * 2048 + p].x, sr);
        atomicAdd(&S[b * 2048 + p].y, si);
    }
}

// ---------------------------------------------------------------------------
// Kernel B: block per batch, 1024 threads. S is already the DIT (bit-reversed)
// input; inverse DIT -> natural order, scale, shuffle-based top-16, softmax.
// ---------------------------------------------------------------------------
__global__ __launch_bounds__(1024) void ifft_topk(const float2* __restrict__ S,
                                                  float* __restrict__ wout,
                                                  int* __restrict__ dout) {
    const int b = blockIdx.x, tid = threadIdx.x;
    __shared__ float2 y[LSEQ];
    __shared__ float  mc[LSEQ];
    __shared__ float  pv[16];
    __shared__ int    pi[16];
    __shared__ float  topv[NDEL];
    __shared__ int    topi[NDEL];

    y[tid]        = S[b * 2048 + tid];
    y[tid + 1024] = S[b * 2048 + tid + 1024];
    __syncthreads();

    for (int M = 2; M <= LSEQ; M <<= 1) {
        const int   half = M >> 1;
        const float w0   = 6.28318530717958647692f / (float)M;
        const int   kk = tid & (half - 1), i0 = 2 * tid - kk, i1 = i0 + half;
        const float2 a = y[i0], bb = y[i1];
        float sn, cs;
        __sincosf(w0 * (float)kk, &sn, &cs);
        const float tx = bb.x * cs - bb.y * sn, ty = bb.x * sn + bb.y * cs;
        y[i0] = make_float2(a.x + tx, a.y + ty);
        y[i1] = make_float2(a.x - tx, a.y - ty);
        __syncthreads();
    }

    const float scale = 1.0f / ((float)LSEQ * (float)(NH * ND));
    mc[tid]        = y[tid].x * scale;
    mc[tid + 1024] = y[tid + 1024].x * scale;
    __syncthreads();

    const int lane = tid & 63, wv = tid >> 6;
    for (int it = 0; it < NDEL; ++it) {
        const float v0 = mc[tid], v1 = mc[tid + 1024];
        float bv; int bix;
        if (v1 > v0) { bv = v1; bix = tid + 1024; } else { bv = v0; bix = tid; }
        #pragma unroll
        for (int off = 32; off; off >>= 1) {
            const float ov = __shfl_xor(bv, off);
            const int   oi = __shfl_xor(bix, off);
            if (ov > bv || (ov == bv && oi < bix)) { bv = ov; bix = oi; }
        }
        if (lane == 0) { pv[wv] = bv; pi[wv] = bix; }
        __syncthreads();
        if (tid < 64) {
            float v = (tid < 16) ? pv[tid] : -3e38f;
            int  ii = (tid < 16) ? pi[tid] : 0;
            #pragma unroll
            for (int off = 8; off; off >>= 1) {
                const float ov = __shfl_xor(v, off);
                const int   oi = __shfl_xor(ii, off);
                if (ov > v || (ov == v && oi < ii)) { v = ov; ii = oi; }
            }
            if (tid == 0) { topv[it] = v; topi[it] = ii; mc[ii] = -3e38f; }
        }
        __syncthreads();
    }

    if (tid == 0) {
        const float m = topv[0];
        float e[NDEL], sum = 0.f;
        for (int t2 = 0; t2 < NDEL; ++t2) { e[t2] = __expf(topv[t2] - m); sum += e[t2]; }
        const float inv = 1.0f / sum;
        for (int t2 = 0; t2 < NDEL; ++t2) {
            wout[b * NDEL + t2] = e[t2] * inv;
            dout[b * NDEL + t2] = topi[t2];
        }
    }
}

// ---------------------------------------------------------------------------
// Kernel C: out[b,h,t,d] = sum_k w[b,k] * v[b,h,(t+delay[b,k]) & 2047, d]
// XCD swizzle: 128 t-tiles of one (b,h) share an XCD (v slice L2-resident).
// ---------------------------------------------------------------------------
__global__ __launch_bounds__(256) void gather_out(const float* __restrict__ v,
                                                  const float* __restrict__ w,
                                                  const int* __restrict__ delay,
                                                  float* __restrict__ out) {
    const int bi  = blockIdx.x;          // 8192 = 64 bh * 128 tiles
    const int xcd = bi & 7;
    const int s   = bi >> 3;             // 0..1023
    const int bh  = xcd * 8 + (s >> 7);
    const int bt  = s & 127;
    const int b   = bh >> 3;
    const int tid = threadIdx.x;

    __shared__ float sw_[NDEL];
    __shared__ int   sd_[NDEL];
    if (tid < NDEL) {
        sw_[tid] = w[b * NDEL + tid];
        sd_[tid] = delay[b * NDEL + tid];
    }
    __syncthreads();

    const float* vb = v + (size_t)bh * LSEQ * ND;
    float*       ob = out + (size_t)bh * LSEQ * ND;

    const int row = tid >> 4;
    const int col = (tid & 15) * 4;
    const int t   = bt * 16 + row;

    float4 acc = make_float4(0.f, 0.f, 0.f, 0.f);
    #pragma unroll
    for (int kk = 0; kk < NDEL; ++kk) {
        const int r = (t + sd_[kk]) & (LSEQ - 1);
        const float4 vv = *(const float4*)(vb + (size_t)r * ND + col);
        const float wv = sw_[kk];
        acc.x += wv * vv.x; acc.y += wv * vv.y;
        acc.z += wv * vv.z; acc.w += wv * vv.w;
    }
    *(float4*)(ob + (size_t)t * ND + col) = acc;
}

// ---------------------------------------------------------------------------
extern "C" void kernel_launch(void* const* d_in, const int* in_sizes, int n_in,
                              void* d_out, int out_size, void* d_ws, size_t ws_size,
                              hipStream_t stream) {
    const float* q = (const float*)d_in[0];
    const float* k = (const float*)d_in[1];
    const float* v = (const float*)d_in[2];
    float* out = (float*)d_out;

    float2* S     = (float2*)((char*)d_ws + WS_S_OFF);
    float*  w     = (float*)((char*)d_ws + WS_W_OFF);
    int*    delay = (int*)((char*)d_ws + WS_DELAY_OFF);

    hipMemsetAsync(d_ws, 0, (size_t)NB * 2048 * sizeof(float2), stream);

    fft_corr<<<dim3(NB * NH * 16), dim3(256), 0, stream>>>(q, k, S);
    ifft_topk<<<dim3(NB), dim3(1024), 0, stream>>>(S, w, delay);
    gather_out<<<dim3(NB * NH * 128), dim3(256), 0, stream>>>(v, w, delay, out);
}